// Round 5
// baseline (173.946 us; speedup 1.0000x reference)
//
#include <hip/hip_runtime.h>

// MoE top-2 of 3x3 SAME convs via bf16 MFMA implicit GEMM — fused single
// main kernel (R5).
//
// R4 evidence: halving A-LDS traffic + halving blocks left dur unchanged
// (60.9 us, MfmaUtil 21%, all pipes <25%) -> limiter is the B-frag global
// gather (16-segment/wave-load, intrinsic to c-major xT) + multi-dispatch
// overhead. R5: (a) kill the xpose dispatch - each block transposes its own
// 6 padded x-rows into an LDS B tile (fp32 scratch -> bf16, XOR-swizzled
// chunks so B-frag ds_read_b128 is conflict-free); (b) A staged per (r,s)
// 16 KB with register prefetch of the next phase during MFMAs.
// LDS: B 44,544 + max(scratch 14,592 | A 16,384 aliased) = 60,928 B
// -> 2 blocks/CU. Per-MFMA LDS = 384 B <= ~412 B budget -> MFMA-limited.

#define BB 64
#define CC 64
#define COO 64
#define HH 56
#define WW 56

typedef __bf16 bf16x8 __attribute__((ext_vector_type(8)));
typedef float  f32x4  __attribute__((ext_vector_type(4)));

// ---- P1: weight pack into A-frag-linear layout (unchanged, verified) ------
// Wpack[e*36864 + (r*3+s)*4096 + ks*2048 + mt*512 + lane*8 + j]
//   = bf16( Wexp[e][mt*16 + (lane&15)][ks*32 + (lane>>4)*8 + j][r][s] )
__global__ __launch_bounds__(256) void wpack_kernel(
    const float* __restrict__ Wexp, __bf16* __restrict__ Wpack)
{
    const int rs = blockIdx.x;          // 0..8  (r*3+s)
    const int e  = blockIdx.y;          // 0..7
    const int r = rs / 3, s = rs % 3;
    for (int idx = threadIdx.x; idx < 4096; idx += 256) {
        const int ks   = idx >> 11;
        const int rem  = idx & 2047;
        const int mt   = rem >> 9;
        const int lane = (rem >> 3) & 63;
        const int j    = idx & 7;
        const int co = mt * 16 + (lane & 15);
        const int c  = ks * 32 + ((lane >> 4) << 3) + j;
        const float v = Wexp[((((size_t)e * COO + co) * CC + c) * 3 + r) * 3 + s];
        Wpack[(size_t)e * 36864 + (size_t)rs * 4096 + idx] = (__bf16)v;
    }
}

// ---- Main: fused transpose + MFMA implicit GEMM ----------------------------
__global__ __launch_bounds__(256, 2) void moe_conv_fused(
    const float* __restrict__ x, const __bf16* __restrict__ Wpack,
    const float* __restrict__ gate_w, const int* __restrict__ gate_i,
    const float* __restrict__ bexp, float* __restrict__ out)
{
    // Bs: [rr=6][wc=58][chunk=8][8 bf16], chunk swizzled: cc' = cc ^ (wc&7)
    // scr (prologue only): fp32 [64][57]    — aliased with ldsA
    // ldsA (phases):  [slot=2][ks=2][mt=4][lane=64][j=8] bf16 = 16 KB
    __shared__ __attribute__((aligned(16))) char smem[44544 + 16384];
    __bf16* Bs   = (__bf16*)smem;
    float*  scr  = (float*)(smem + 44544);
    __bf16* ldsA = (__bf16*)(smem + 44544);

    const int b   = blockIdx.y;
    const int h0  = blockIdx.x * 4;     // output rows h0..h0+3
    const int tid = threadIdx.x;
    const int wid = tid >> 6, lane = tid & 63;
    const int n15 = lane & 15, quad = lane >> 4;
    const int wcol = wid * 16 + n15;    // output col 0..63 (>=56 discarded)

    const int   e0 = gate_i[b * 2 + 0], e1 = gate_i[b * 2 + 1];
    const float g0 = gate_w[b * 2 + 0], g1 = gate_w[b * 2 + 1];

    const __bf16* s0p = Wpack + (size_t)e0 * 36864;
    const __bf16* s1p = Wpack + (size_t)e1 * 36864;

    // Preload phase-0 A into regs early (hides behind prologue).
    uint4 apre[4];
    #pragma unroll
    for (int i = 0; i < 4; ++i)
        apre[i] = *(const uint4*)((i < 2 ? s0p : s1p) + (size_t)((i & 1) * 256 + tid) * 8);

    // ---- prologue: build swizzled bf16 B tile from raw NCHW x --------------
    #pragma unroll 1
    for (int rr = 0; rr < 6; ++rr) {
        const int h = h0 + rr - 1;                   // input row
        const bool valid = (h >= 0) && (h < HH);
        if (valid) {
            for (int i = tid; i < CC * 14; i += 256) {
                const int c = i / 14, wq = i - c * 14;
                const float4 f = *(const float4*)(
                    x + (((size_t)b * CC + c) * HH + h) * WW + wq * 4);
                float* sp = &scr[c * 57 + wq * 4];
                sp[0] = f.x; sp[1] = f.y; sp[2] = f.z; sp[3] = f.w;
            }
        }
        __syncthreads();
        for (int j = tid; j < 58 * 8; j += 256) {
            const int wc = j >> 3, cg = j & 7;
            bf16x8 v = {};
            if (valid && wc >= 1 && wc <= WW) {
                const int w = wc - 1;
                #pragma unroll
                for (int u = 0; u < 8; ++u) v[u] = (__bf16)scr[(cg * 8 + u) * 57 + w];
            }
            *(bf16x8*)&Bs[(size_t)(((rr * 58 + wc) * 8) + (cg ^ (wc & 7))) * 8] = v;
        }
        __syncthreads();
    }

    f32x4 acc[2][4][4] = {};            // [slot][mt][row t]

    // ---- 9 phases: one (r,s) tap each ----------------------------------------
    #pragma unroll 1
    for (int p = 0; p < 9; ++p) {
        const int r = p / 3, s = p - r * 3;

        __syncthreads();                // all waves done with A[p-1] / prologue
        #pragma unroll
        for (int i = 0; i < 4; ++i)     // ldsA is linear copy of Wpack slice
            *(uint4*)&ldsA[(size_t)(i * 256 + tid) * 8] = apre[i];
        if (p < 8) {                    // prefetch next phase during MFMAs
            #pragma unroll
            for (int i = 0; i < 4; ++i)
                apre[i] = *(const uint4*)((i < 2 ? s0p : s1p)
                          + (size_t)(p + 1) * 4096 + (size_t)((i & 1) * 256 + tid) * 8);
        }
        __syncthreads();                // A[p] visible

        const int wc1 = min(wcol + s, 57);   // clamped lanes -> discarded cols
        #pragma unroll
        for (int ks = 0; ks < 2; ++ks) {
            bf16x8 bfr[4];
            #pragma unroll
            for (int t = 0; t < 4; ++t) {
                const int rr = t + r;
                const int cb = ((rr * 58 + wc1) * 8) + ((ks * 4 + quad) ^ (wc1 & 7));
                bfr[t] = *(const bf16x8*)&Bs[(size_t)cb * 8];
            }
            #pragma unroll
            for (int slot = 0; slot < 2; ++slot) {
                #pragma unroll
                for (int mt = 0; mt < 4; ++mt) {
                    const bf16x8 af = *(const bf16x8*)
                        &ldsA[(size_t)(slot * 4096 + ks * 2048 + mt * 512 + lane * 8)];
                    #pragma unroll
                    for (int t = 0; t < 4; ++t)
                        acc[slot][mt][t] = __builtin_amdgcn_mfma_f32_16x16x32_bf16(
                            af, bfr[t], acc[slot][mt][t], 0, 0, 0);
                }
            }
        }
    }

    // ---- epilogue: D layout col=lane&15 (pixel), row=quad*4+reg ------------
    if (wcol < WW) {
        #pragma unroll
        for (int t = 0; t < 4; ++t) {
            const int h = h0 + t;
            #pragma unroll
            for (int mt = 0; mt < 4; ++mt) {
                #pragma unroll
                for (int v = 0; v < 4; ++v) {
                    const int co = mt * 16 + quad * 4 + v;
                    float a0 = acc[0][mt][t][v] + bexp[e0 * COO + co];
                    float a1 = acc[1][mt][t][v] + bexp[e1 * COO + co];
                    a0 = fmaxf(a0, 0.f);
                    a1 = fmaxf(a1, 0.f);
                    out[(((size_t)b * COO + co) * HH + h) * WW + wcol] =
                        g0 * a0 + g1 * a1;
                }
            }
        }
    }
}

extern "C" void kernel_launch(void* const* d_in, const int* in_sizes, int n_in,
                              void* d_out, int out_size, void* d_ws, size_t ws_size,
                              hipStream_t stream) {
    const float* x      = (const float*)d_in[0];
    const float* gate_w = (const float*)d_in[1];
    const int*   gate_i = (const int*)  d_in[2];
    const float* Wexp   = (const float*)d_in[3];
    const float* bexp   = (const float*)d_in[4];
    float* out = (float*)d_out;

    __bf16* Wpack = (__bf16*)d_ws;      // 589,824 B; nothing else in ws

    wpack_kernel<<<dim3(9, 8), 256, 0, stream>>>(Wexp, Wpack);
    moe_conv_fused<<<dim3(14, BB), 256, 0, stream>>>(x, Wpack, gate_w, gate_i,
                                                     bexp, out);
}

// Round 6
// 161.954 us; speedup vs baseline: 1.0740x; 1.0740x over previous
//
#include <hip/hip_runtime.h>

// MoE top-2 of 3x3 SAME convs via bf16 MFMA implicit GEMM.
//
// R6: R5's fused B-build regressed main 60.9->103.4 us (barrier-starved MFMA
// at 2 blocks/CU + 6M LDS conflicts). Revert main to R4's proven kernel
// (60.9 us). Attack the ~100 us of non-main time instead: merge xpose+wpack
// into ONE prep kernel (2 dispatches total, 1 dependency boundary) to
// measure/eliminate per-dispatch-boundary cost.
//
// P0+P1 (prep): blocks 0..959  = xpose, 4 hp-rows per block:
//                 x [B,C,H,W] f32 -> xT [B][58][66][C] bf16 zero-padded.
//               blocks 960..1031 = wpack:
//                 Wexp f32 -> Wpack bf16 A-frag-linear [e][rs][ks][mt][lane][j].
// Main (R4 verbatim): block = 4 waves = 64co x 64px x 4rows per (b, row-quad);
// A staged per-r in LDS (48 KB); B-frags direct from L2/L3-resident xT.

#define BB 64
#define CC 64
#define COO 64
#define HH 56
#define WW 56

typedef __bf16 bf16x8 __attribute__((ext_vector_type(8)));
typedef float  f32x4  __attribute__((ext_vector_type(4)));

// ---- prep: fused transpose (fat blocks) + weight pack ----------------------
__global__ __launch_bounds__(256) void prep_kernel(
    const float* __restrict__ x, const float* __restrict__ Wexp,
    __bf16* __restrict__ xT, __bf16* __restrict__ Wpack)
{
    const int bx  = blockIdx.x;
    const int tid = threadIdx.x;

    if (bx < 960) {
        // ---- xpose part: 4 hp-rows per block -------------------------------
        __shared__ float tile[CC][WW + 1];   // stride 57: reads 2-way max
        const int b   = bx / 15;
        const int grp = bx - b * 15;         // 0..14 -> hp = grp*4 + rr
        #pragma unroll 1
        for (int rr = 0; rr < 4; ++rr) {
            const int hp = grp * 4 + rr;
            if (hp >= 58) break;
            __bf16* dst = xT + ((size_t)b * 58 + hp) * 66 * CC;
            const bool interior = (hp >= 1 && hp <= HH);
            if (!interior) {                 // pad row: zero-fill (no LDS use)
                bf16x8 z = {};
                for (int j = tid; j < 66 * CC / 8; j += 256)
                    *(bf16x8*)(dst + j * 8) = z;
                continue;                    // hp uniform per block: no diverge
            }
            const int h = hp - 1;
            const float* xb = x + (size_t)b * CC * HH * WW + (size_t)h * WW;
            for (int i = tid; i < CC * 14; i += 256) {
                const int c = i / 14, wq = i - c * 14;
                const float4 f = *(const float4*)(xb + (size_t)c * HH * WW + wq * 4);
                tile[c][wq * 4 + 0] = f.x; tile[c][wq * 4 + 1] = f.y;
                tile[c][wq * 4 + 2] = f.z; tile[c][wq * 4 + 3] = f.w;
            }
            __syncthreads();
            for (int j = tid; j < 66 * 8; j += 256) {
                const int wc = j >> 3, cg = j & 7;
                bf16x8 v = {};
                if (wc >= 1 && wc <= WW) {
                    const int w = wc - 1;
                    #pragma unroll
                    for (int u = 0; u < 8; ++u)
                        v[u] = (__bf16)tile[cg * 8 + u][w];
                }
                *(bf16x8*)(dst + wc * CC + cg * 8) = v;   // 16B coalesced
            }
            __syncthreads();                 // before next rr reuses tile
        }
    } else {
        // ---- wpack part (verified R3+ body) --------------------------------
        // Wpack[e*36864 + rs*4096 + ks*2048 + mt*512 + lane*8 + j]
        //   = bf16( Wexp[e][mt*16+(lane&15)][ks*32+(lane>>4)*8+j][r][s] )
        const int wp = bx - 960;             // 0..71
        const int e  = wp / 9, rs = wp - e * 9;
        const int r  = rs / 3, s  = rs - r * 3;
        for (int idx = tid; idx < 4096; idx += 256) {
            const int ks   = idx >> 11;
            const int rem  = idx & 2047;
            const int mt   = rem >> 9;
            const int lane = (rem >> 3) & 63;
            const int j    = idx & 7;
            const int co = mt * 16 + (lane & 15);
            const int c  = ks * 32 + ((lane >> 4) << 3) + j;
            const float v = Wexp[((((size_t)e * COO + co) * CC + c) * 3 + r) * 3 + s];
            Wpack[(size_t)e * 36864 + (size_t)rs * 4096 + idx] = (__bf16)v;
        }
    }
}

// ---- Main: MFMA implicit GEMM, 4 rows/block (R4 verbatim, 60.9 us) ---------
__global__ __launch_bounds__(256, 2) void moe_conv_mfma(
    const __bf16* __restrict__ xT, const __bf16* __restrict__ Wpack,
    const float* __restrict__ gate_w, const int* __restrict__ gate_i,
    const float* __restrict__ bexp, float* __restrict__ out)
{
    __shared__ __bf16 ldsA[2 * 12288];  // [slot][s][ks][mt][lane][j] = 48 KB

    const int b   = blockIdx.y;
    const int h0  = blockIdx.x * 4;     // rows h0..h0+3
    const int tid = threadIdx.x;
    const int wid = tid >> 6, lane = tid & 63;
    const int n15 = lane & 15, quad = lane >> 4;
    const int wcol = wid * 16 + n15;    // padded col 0..63

    const int   e0 = gate_i[b * 2 + 0], e1 = gate_i[b * 2 + 1];
    const float g0 = gate_w[b * 2 + 0], g1 = gate_w[b * 2 + 1];

    const __bf16* xb = xT + (size_t)b * 58 * 66 * CC;

    f32x4 acc[2][4][4] = {};            // [slot][mt][row t]

    for (int r = 0; r < 3; ++r) {
        __syncthreads();                // prior r's LDS readers done
        {   // stage both slots' (r, all s) A-frags: 48 chunks of 1 KB
            const __bf16* s0 = Wpack + (size_t)e0 * 36864 + r * 12288;
            const __bf16* s1 = Wpack + (size_t)e1 * 36864 + r * 12288;
            #pragma unroll
            for (int i = 0; i < 12; ++i) {
                const int q    = wid * 12 + i;       // 0..47
                const int slot = q >= 24;
                const int rem  = q - slot * 24;
                const __bf16* src = (slot ? s1 : s0) + rem * 512 + lane * 8;
                const uint4 tmp = *(const uint4*)src;
                *(uint4*)&ldsA[q * 512 + lane * 8] = tmp;
            }
        }
        __syncthreads();

        #pragma unroll
        for (int s = 0; s < 3; ++s) {
            #pragma unroll
            for (int ks = 0; ks < 2; ++ks) {
                bf16x8 bf[4];
                #pragma unroll
                for (int t = 0; t < 4; ++t) {
                    const int hr1 = h0 + t + r;      // padded row 0..57
                    const int wc1 = wcol + s;        // padded col 0..65
                    bf[t] = *(const bf16x8*)(
                        xb + (size_t)(hr1 * 66 + wc1) * CC + ks * 32 + quad * 8);
                }
                #pragma unroll
                for (int slot = 0; slot < 2; ++slot) {
                    #pragma unroll
                    for (int mt = 0; mt < 4; ++mt) {
                        const bf16x8 af = *(const bf16x8*)
                            &ldsA[slot * 12288 + (s * 2 + ks) * 2048 + mt * 512 + lane * 8];
                        #pragma unroll
                        for (int t = 0; t < 4; ++t)
                            acc[slot][mt][t] = __builtin_amdgcn_mfma_f32_16x16x32_bf16(
                                af, bf[t], acc[slot][mt][t], 0, 0, 0);
                    }
                }
            }
        }
    }

    // Epilogue: D layout col=lane&15 (pixel), row=quad*4+reg (co within mt)
    if (wcol < WW) {
        #pragma unroll
        for (int t = 0; t < 4; ++t) {
            const int h = h0 + t;
            #pragma unroll
            for (int mt = 0; mt < 4; ++mt) {
                #pragma unroll
                for (int v = 0; v < 4; ++v) {
                    const int co = mt * 16 + quad * 4 + v;
                    float a0 = acc[0][mt][t][v] + bexp[e0 * COO + co];
                    float a1 = acc[1][mt][t][v] + bexp[e1 * COO + co];
                    a0 = fmaxf(a0, 0.f);
                    a1 = fmaxf(a1, 0.f);
                    out[(((size_t)b * COO + co) * HH + h) * WW + wcol] =
                        g0 * a0 + g1 * a1;
                }
            }
        }
    }
}

extern "C" void kernel_launch(void* const* d_in, const int* in_sizes, int n_in,
                              void* d_out, int out_size, void* d_ws, size_t ws_size,
                              hipStream_t stream) {
    const float* x      = (const float*)d_in[0];
    const float* gate_w = (const float*)d_in[1];
    const int*   gate_i = (const int*)  d_in[2];
    const float* Wexp   = (const float*)d_in[3];
    const float* bexp   = (const float*)d_in[4];
    float* out = (float*)d_out;

    // Wpack first (fixed 589,824 B, 16B-aligned), then xT (31,358,976 B).
    __bf16* Wpack = (__bf16*)d_ws;
    __bf16* xT    = (__bf16*)((char*)d_ws + 589824);

    prep_kernel<<<dim3(1032), 256, 0, stream>>>(x, Wexp, xT, Wpack);
    moe_conv_mfma<<<dim3(14, BB), 256, 0, stream>>>(xT, Wpack, gate_w, gate_i,
                                                    bexp, out);
}